// Round 13
// baseline (123.752 us; speedup 1.0000x reference)
//
#include <hip/hip_runtime.h>
#include <hip/hip_bf16.h>
#include <stdint.h>

#define N_ROWS 512
#define D_DIM  512
#define C_CLS  100000

#define SCALE_F    64.0f
#define EPS_F      1e-7f
#define COS_M_F    0.8775825618903728f
#define SIN_M_F    0.4794255386042030f
#define THRESH_F  -0.8775825618903728f
#define MM_F       0.2397127693021015f
#define FIXMAX_F   65.0f        // fixed softmax max: all logits <= ~64.7 < 65

#define NC  64          // classes per block
#define NG2 1564        // ceil(100000/64) -> 1564*64 = 100096

// ---- ws layout (bytes) ----
#define XN8_OFF    0                          // fp8 [512][512] = 256 KB
#define TL_OFF     (XN8_OFF + 512*512)        // f32 [512]
#define CTM_OFF    (TL_OFF + 2048)            // f32 [512]
#define FTL_OFF    (CTM_OFF + 2048)           // f32 [512]
#define TNEW_OFF   (FTL_OFF + 2048)           // f32 [1] (padded)
#define XNORM_OFF  (TNEW_OFF + 256)           // f32 [512]
#define PSUM_OFF   (XNORM_OFF + 2048)         // f32 [NG2][512] = 3.2 MB (transposed)
#define LOSSI_OFF  (PSUM_OFF + NG2*512*4)     // f32 [512]

typedef __attribute__((ext_vector_type(4))) float f32x4;

#define GLOAD_LDS16(gp, lp) \
    __builtin_amdgcn_global_load_lds((const __attribute__((address_space(1))) void*)(gp), \
                                     (__attribute__((address_space(3))) void*)(lp), 16, 0, 0)

#if defined(__has_builtin)
#if __has_builtin(__builtin_amdgcn_cvt_pk_fp8_f32)
#define HAVE_CVT_FP8 1
#endif
#endif

// manual OCP e4m3fn fallback (round-to-nearest; saturating; no inf)
__device__ inline unsigned char f2e4m3(float f) {
    union { float f; unsigned u; } a; a.f = f;
    unsigned s = (a.u >> 24) & 0x80u;
    float af = fabsf(f);
    if (af < 0.015625f) {
        int q = (int)(af * 512.0f + 0.5f);
        return (unsigned char)(s | (unsigned)q);
    }
    unsigned x = a.u & 0x7FFFFFFFu;
    unsigned r = x + 0x000FFFFFu + ((x >> 20) & 1u);
    int ec = (int)(r >> 23) - 127 + 7;
    unsigned m = (r >> 20) & 7u;
    if (ec > 15 || (ec == 15 && m == 7u)) return (unsigned char)(s | 0x7Eu);
    return (unsigned char)(s | ((unsigned)ec << 3) | m);
}

__device__ inline unsigned pack4_fp8(float f0, float f1, float f2, float f3) {
#ifdef HAVE_CVT_FP8
    int q = __builtin_amdgcn_cvt_pk_fp8_f32(f0, f1, 0, false);
    q     = __builtin_amdgcn_cvt_pk_fp8_f32(f2, f3, q, true);
    return (unsigned)q;
#else
    union { unsigned char b[4]; unsigned u; } u;
    u.b[0]=f2e4m3(f0); u.b[1]=f2e4m3(f1); u.b[2]=f2e4m3(f2); u.b[3]=f2e4m3(f3);
    return u.u;
#endif
}

__device__ inline uint2 pack8_fp8(float f0, float f1, float f2, float f3,
                                  float f4, float f5, float f6, float f7) {
    uint2 r;
    r.x = pack4_fp8(f0, f1, f2, f3);
    r.y = pack4_fp8(f4, f5, f6, f7);
    return r;
}

__device__ inline float wave_sum64(float v) {
    #pragma unroll
    for (int m = 1; m < 64; m <<= 1) v += __shfl_xor(v, m);
    return v;
}

// K1: x row norms + xn fp8.  grid 512 x 64
__global__ void k_xnorm_fp8(const float* __restrict__ x,
                            unsigned char* __restrict__ xn8,
                            float* __restrict__ xnorm) {
    int row = blockIdx.x;
    int lane = threadIdx.x;
    const float* xr = x + row * D_DIM + lane * 8;
    float4 v0 = *(const float4*)(xr);
    float4 v1 = *(const float4*)(xr + 4);
    float s = v0.x*v0.x + v0.y*v0.y + v0.z*v0.z + v0.w*v0.w
            + v1.x*v1.x + v1.y*v1.y + v1.z*v1.z + v1.w*v1.w;
    s = wave_sum64(s);
    float nrm = sqrtf(s);
    if (lane == 0) xnorm[row] = nrm;
    float inv = 1.0f / nrm;
    uint2 q = pack8_fp8(v0.x*inv, v0.y*inv, v0.z*inv, v0.w*inv,
                        v1.x*inv, v1.y*inv, v1.z*inv, v1.w*inv);
    *(uint2*)(xn8 + row * D_DIM + lane * 8) = q;
}

// K2: per-row target logit + margin terms; target w-norm computed inline.
// grid 512 x 64
__global__ void k_tlogit(const float* __restrict__ x, const float* __restrict__ w,
                         const float* __restrict__ xnorm,
                         const int* __restrict__ target,
                         float* __restrict__ tl, float* __restrict__ ctm,
                         float* __restrict__ ftl) {
    int row = blockIdx.x;
    int lane = threadIdx.x;
    int tgt = target[row];
    const float* xr = x + row * D_DIM + lane * 8;
    const float* wr = w + (size_t)tgt * D_DIM + lane * 8;
    float4 a0 = *(const float4*)(xr),     a1 = *(const float4*)(xr + 4);
    float4 b0 = *(const float4*)(wr),     b1 = *(const float4*)(wr + 4);
    float s = a0.x*b0.x + a0.y*b0.y + a0.z*b0.z + a0.w*b0.w
            + a1.x*b1.x + a1.y*b1.y + a1.z*b1.z + a1.w*b1.w;
    float q = b0.x*b0.x + b0.y*b0.y + b0.z*b0.z + b0.w*b0.w
            + b1.x*b1.x + b1.y*b1.y + b1.z*b1.z + b1.w*b1.w;
    s = wave_sum64(s);
    q = wave_sum64(q);
    if (lane == 0) {
        float c = s / (xnorm[row] * sqrtf(q));
        c = fminf(fmaxf(c, -1.0f + EPS_F), 1.0f - EPS_F);
        float sn = sqrtf(fmaxf(1.0f - c * c, 0.0f));
        float cm = c * COS_M_F - sn * SIN_M_F;
        tl[row]  = c;
        ctm[row] = cm;
        ftl[row] = (c > THRESH_F) ? cm : (c - MM_F);
    }
}

// K2b: t_new = mean(tl)*0.01 + 0.99*t.  1 x 512
__global__ void k_tnew(const float* __restrict__ tl, const float* __restrict__ t,
                       float* __restrict__ tnew) {
    __shared__ float s[512];
    int tid = threadIdx.x;
    s[tid] = tl[tid];
    __syncthreads();
    for (int off = 256; off > 0; off >>= 1) {
        if (tid < off) s[tid] += s[tid + off];
        __syncthreads();
    }
    if (tid == 0) tnew[0] = (s[0] / 512.0f) * 0.01f + 0.99f * t[0];
}

// ---------------------------------------------------------------------------
// K3: FUSED single-pass kernel.  Each block: ALL 512 rows x 64 classes.
//  - w (f32) read exactly ONCE chip-wide; B pipeline has THREE slices of
//    lead (rv_next/rv_far in-flight registers): ds_write of slice kk+1 uses
//    a load issued at step kk-2 -> ~1800 cyc of latency cover (HBM ~900).
//  - A (xn8, 256 KB, L2-resident) streams per-step via global_load_lds dbuf.
//  - per wave per step: 16 MFMA (fp8 16x16x32); one barrier per step.
//  - 1/||w|| applied as a column scale in the epilogue.
//  - fixed softmax max (=65): exp+sum only; psum TRANSPOSED [bx][row] so the
//    block's partial writes are coalesced.
// grid 1564 x 512
// ---------------------------------------------------------------------------
__global__ __launch_bounds__(512, 4) void k_fused(
        const unsigned char* __restrict__ xn8,    // fp8 [512][512], normalized
        const float* __restrict__ w,              // f32 [100000][512] RAW
        const int* __restrict__ target,
        const float* __restrict__ ctm,
        const float* __restrict__ ftl,
        const float* __restrict__ tnew,
        float* __restrict__ psum) {               // [NG2][512]
    __shared__ unsigned char As[2][512 * 32];     // 2 x 16 KB
    __shared__ unsigned char Bs[2][64 * 32];      // 2 x 2 KB
    __shared__ float invS[64];
    __shared__ int   tgt_s[512];
    __shared__ float ctm_s[512];
    __shared__ float ftl_s[512];

    int bx = blockIdx.x;
    int cb = bx * NC;                  // first class of this block
    int tid = threadIdx.x;
    int lane = tid & 63, wid = tid >> 6;
    int fr = lane & 15, rgrp = lane >> 4;
    int wrow = wid * 64;               // wave's first A-row

    tgt_s[tid] = target[tid];
    ctm_s[tid] = ctm[tid];
    ftl_s[tid] = ftl[tid];

    // ---- B staging assignment: thread -> (class-row, 4-f32 slot) ----
    int brow  = tid >> 3;              // 0..63
    int bslot = tid & 7;               // 0..7
    int bclass = cb + brow;
    bool brvalid = (bclass < C_CLS);
    const float* bsrc = w + (size_t)(brvalid ? bclass : 0) * D_DIM + bslot * 4;

    float sumsq = 0.0f;

    // stage A slice kk into As[buf] (2 x 8 KB global_load_lds, linear)
    #define STAGE_A(kk, buf)                                                  \
        do {                                                                  \
            _Pragma("unroll")                                                 \
            for (int c = 0; c < 2; ++c) {                                     \
                int lo = c * 8192 + wid * 1024;      /* wave-uniform */       \
                int o  = lo + lane * 16;                                      \
                int row = o >> 5, b = o & 31;                                 \
                GLOAD_LDS16(xn8 + (size_t)row * 512 + (kk) * 32 + b,          \
                            (char*)As[buf] + lo);                             \
            }                                                                 \
        } while (0)

    // write a previously-loaded B slice into Bs[buf]: sumsq + cvt + ds_write
    #define WRITE_B(vv, buf)                                                  \
        do {                                                                  \
            sumsq += vv.x*vv.x + vv.y*vv.y + vv.z*vv.z + vv.w*vv.w;           \
            *(unsigned*)(&Bs[buf][brow * 32 + bslot * 4]) =                   \
                pack4_fp8(vv.x, vv.y, vv.z, vv.w);                            \
        } while (0)

    // prologue: slice 0 direct; slices 1,2 in flight
    float4 rv_next = *(const float4*)(bsrc + 1 * 32);   // slice 1
    float4 rv_far  = *(const float4*)(bsrc + 2 * 32);   // slice 2
    {
        float4 v0 = *(const float4*)(bsrc);
        WRITE_B(v0, 0);
    }
    STAGE_A(0, 0);
    __syncthreads();

    float tn = tnew[0];

    f32x4 acc[4][4];                   // [m][j]
    #pragma unroll
    for (int m = 0; m < 4; m++)
        #pragma unroll
        for (int j = 0; j < 4; j++)
            acc[m][j] = (f32x4){0.f, 0.f, 0.f, 0.f};

    union LL { uint2 u; long long ll; };

    #pragma unroll
    for (int kk = 0; kk < 16; ++kk) {
        int cur = kk & 1;
        if (kk < 15) {
            // write slice kk+1 (loaded >= 2 steps ago), rotate in-flight regs
            WRITE_B(rv_next, cur ^ 1);
            rv_next = rv_far;
            if (kk < 13)
                rv_far = *(const float4*)(bsrc + (kk + 3) * 32);
            STAGE_A(kk + 1, cur ^ 1);
        }
        // frags from current buffers
        uint2 af[4], bf[4];
        #pragma unroll
        for (int m = 0; m < 4; m++)
            af[m] = *(const uint2*)(&As[cur][(wrow + m * 16 + fr) * 32 + rgrp * 8]);
        #pragma unroll
        for (int j = 0; j < 4; j++)
            bf[j] = *(const uint2*)(&Bs[cur][(j * 16 + fr) * 32 + rgrp * 8]);
        __builtin_amdgcn_s_setprio(1);
        #pragma unroll
        for (int m = 0; m < 4; m++)
            #pragma unroll
            for (int j = 0; j < 4; j++) {
                LL a, b;
                a.u = af[m];
                b.u = bf[j];
                acc[m][j] = __builtin_amdgcn_mfma_f32_16x16x32_fp8_fp8(
                                a.ll, b.ll, acc[m][j], 0, 0, 0);
            }
        __builtin_amdgcn_s_setprio(0);
        __syncthreads();               // next-slice staged; buffers handoff
    }
    #undef STAGE_A
    #undef WRITE_B

    // ---- combine sumsq (8 threads per class row) -> invS ----
    float s2 = sumsq;
    s2 += __shfl_xor(s2, 1);
    s2 += __shfl_xor(s2, 2);
    s2 += __shfl_xor(s2, 4);
    if (bslot == 0) invS[brow] = rsqrtf(s2);
    __syncthreads();

    // ---- epilogue: fixed-max transform + exp + row sum ----
    // C/D layout: col = cb + j*16 + fr, row = wrow + m*16 + rgrp*4 + reg.
    float inv[4];
    bool cvalid[4];
    #pragma unroll
    for (int j = 0; j < 4; j++) {
        inv[j] = invS[j * 16 + fr];
        cvalid[j] = (cb + j * 16 + fr) < C_CLS;
    }
    #pragma unroll
    for (int m = 0; m < 4; m++) {
        #pragma unroll
        for (int reg = 0; reg < 4; reg++) {
            int rl = wrow + m * 16 + rgrp * 4 + reg;
            int tr = tgt_s[rl];
            float cm = ctm_s[rl];
            float ft = ftl_s[rl];
            float sm = 0.0f;
            #pragma unroll
            for (int j = 0; j < 4; j++) {
                int col = cb + j * 16 + fr;
                float c = acc[m][j][reg] * inv[j];
                c = fminf(fmaxf(c, -1.0f + EPS_F), 1.0f - EPS_F);
                float v = (c > cm) ? c * (tn + c) : c;
                v *= SCALE_F;
                v = (col == tr) ? ft * SCALE_F : v;
                v = cvalid[j] ? v : -3.0e38f;   // exp -> 0
                sm += __expf(v - FIXMAX_F);
            }
            #pragma unroll
            for (int msk = 1; msk < 16; msk <<= 1) sm += __shfl_xor(sm, msk);
            if (fr == 0) psum[(size_t)bx * 512 + rl] = sm;   // coalesced
        }
    }
}

// K4: per-row sum over NG2 partials (fixed max) -> loss_i.  grid 512 x 256
// psum is [nb][row]; reads are strided but L2-resident (3.2 MB).
__global__ void k_rowlse_fix(const float* __restrict__ psum,
                             const float* __restrict__ ftl,
                             float* __restrict__ lossi) {
    int row = blockIdx.x, tid = threadIdx.x;
    float S = 0.0f;
    for (int nb = tid; nb < NG2; nb += 256) S += psum[(size_t)nb * 512 + row];
    __shared__ float sS[256];
    sS[tid] = S;
    __syncthreads();
    for (int off = 128; off > 0; off >>= 1) {
        if (tid < off) sS[tid] += sS[tid + off];
        __syncthreads();
    }
    if (tid == 0) lossi[row] = logf(sS[0]) + FIXMAX_F - SCALE_F * ftl[row];
}

// K5: loss = mean(loss_i).  1 x 512
__global__ void k_final(const float* __restrict__ lossi, float* __restrict__ out) {
    __shared__ float s[512];
    int tid = threadIdx.x;
    s[tid] = lossi[tid];
    __syncthreads();
    for (int off = 256; off > 0; off >>= 1) {
        if (tid < off) s[tid] += s[tid + off];
        __syncthreads();
    }
    if (tid == 0) out[0] = s[0] / 512.0f;
}

extern "C" void kernel_launch(void* const* d_in, const int* in_sizes, int n_in,
                              void* d_out, int out_size, void* d_ws, size_t ws_size,
                              hipStream_t stream) {
    const float* x      = (const float*)d_in[0];
    const float* w      = (const float*)d_in[1];
    const float* t      = (const float*)d_in[2];
    const int*   target = (const int*)d_in[3];

    char* ws = (char*)d_ws;
    unsigned char* xn8  = (unsigned char*)(ws + XN8_OFF);
    float* tl    = (float*)(ws + TL_OFF);
    float* ctm   = (float*)(ws + CTM_OFF);
    float* ftl   = (float*)(ws + FTL_OFF);
    float* tnew  = (float*)(ws + TNEW_OFF);
    float* xnorm = (float*)(ws + XNORM_OFF);
    float* psum  = (float*)(ws + PSUM_OFF);
    float* lossi = (float*)(ws + LOSSI_OFF);
    float* out   = (float*)d_out;

    k_xnorm_fp8<<<dim3(N_ROWS), dim3(64), 0, stream>>>(x, xn8, xnorm);
    k_tlogit<<<dim3(N_ROWS), dim3(64), 0, stream>>>(x, w, xnorm, target, tl, ctm, ftl);
    k_tnew<<<dim3(1), dim3(512), 0, stream>>>(tl, t, tnew);
    k_fused<<<dim3(NG2), dim3(512), 0, stream>>>(xn8, w, target, ctm, ftl, tnew, psum);
    k_rowlse_fix<<<dim3(N_ROWS), dim3(256), 0, stream>>>(psum, ftl, lossi);
    k_final<<<dim3(1), dim3(512), 0, stream>>>(lossi, out);
}

// Round 14
// 122.805 us; speedup vs baseline: 1.0077x; 1.0077x over previous
//
#include <hip/hip_runtime.h>
#include <hip/hip_bf16.h>
#include <stdint.h>

#define N_ROWS 512
#define D_DIM  512
#define C_CLS  100000

#define SCALE_F    64.0f
#define EPS_F      1e-7f
#define COS_M_F    0.8775825618903728f
#define SIN_M_F    0.4794255386042030f
#define THRESH_F  -0.8775825618903728f
#define MM_F       0.2397127693021015f
#define FIXMAX_F   65.0f        // fixed softmax max: all logits <= ~64.7 < 65

#define NC  64          // classes per block
#define NG2 1564        // ceil(100000/64) -> 1564*64 = 100096

// ---- ws layout (bytes) ----
#define XN8_OFF    0                          // fp8 [512][512] = 256 KB
#define TL_OFF     (XN8_OFF + 512*512)        // f32 [512]
#define CTM_OFF    (TL_OFF + 2048)            // f32 [512]
#define FTL_OFF    (CTM_OFF + 2048)           // f32 [512]
#define TNEW_OFF   (FTL_OFF + 2048)           // f32 [1] (padded)
#define XNORM_OFF  (TNEW_OFF + 256)           // f32 [512]
#define PSUM_OFF   (XNORM_OFF + 2048)         // f32 [NG2][512] = 3.2 MB (transposed)
#define LOSSI_OFF  (PSUM_OFF + NG2*512*4)     // f32 [512]

typedef __attribute__((ext_vector_type(4))) float f32x4;

#define GLOAD_LDS16(gp, lp) \
    __builtin_amdgcn_global_load_lds((const __attribute__((address_space(1))) void*)(gp), \
                                     (__attribute__((address_space(3))) void*)(lp), 16, 0, 0)

#if defined(__has_builtin)
#if __has_builtin(__builtin_amdgcn_cvt_pk_fp8_f32)
#define HAVE_CVT_FP8 1
#endif
#endif

// manual OCP e4m3fn fallback (round-to-nearest; saturating; no inf)
__device__ inline unsigned char f2e4m3(float f) {
    union { float f; unsigned u; } a; a.f = f;
    unsigned s = (a.u >> 24) & 0x80u;
    float af = fabsf(f);
    if (af < 0.015625f) {
        int q = (int)(af * 512.0f + 0.5f);
        return (unsigned char)(s | (unsigned)q);
    }
    unsigned x = a.u & 0x7FFFFFFFu;
    unsigned r = x + 0x000FFFFFu + ((x >> 20) & 1u);
    int ec = (int)(r >> 23) - 127 + 7;
    unsigned m = (r >> 20) & 7u;
    if (ec > 15 || (ec == 15 && m == 7u)) return (unsigned char)(s | 0x7Eu);
    return (unsigned char)(s | ((unsigned)ec << 3) | m);
}

__device__ inline unsigned pack4_fp8(float f0, float f1, float f2, float f3) {
#ifdef HAVE_CVT_FP8
    int q = __builtin_amdgcn_cvt_pk_fp8_f32(f0, f1, 0, false);
    q     = __builtin_amdgcn_cvt_pk_fp8_f32(f2, f3, q, true);
    return (unsigned)q;
#else
    union { unsigned char b[4]; unsigned u; } u;
    u.b[0]=f2e4m3(f0); u.b[1]=f2e4m3(f1); u.b[2]=f2e4m3(f2); u.b[3]=f2e4m3(f3);
    return u.u;
#endif
}

__device__ inline uint2 pack8_fp8(float f0, float f1, float f2, float f3,
                                  float f4, float f5, float f6, float f7) {
    uint2 r;
    r.x = pack4_fp8(f0, f1, f2, f3);
    r.y = pack4_fp8(f4, f5, f6, f7);
    return r;
}

__device__ inline float wave_sum64(float v) {
    #pragma unroll
    for (int m = 1; m < 64; m <<= 1) v += __shfl_xor(v, m);
    return v;
}

// K1: x row norms + xn fp8.  grid 512 x 64
__global__ void k_xnorm_fp8(const float* __restrict__ x,
                            unsigned char* __restrict__ xn8,
                            float* __restrict__ xnorm) {
    int row = blockIdx.x;
    int lane = threadIdx.x;
    const float* xr = x + row * D_DIM + lane * 8;
    float4 v0 = *(const float4*)(xr);
    float4 v1 = *(const float4*)(xr + 4);
    float s = v0.x*v0.x + v0.y*v0.y + v0.z*v0.z + v0.w*v0.w
            + v1.x*v1.x + v1.y*v1.y + v1.z*v1.z + v1.w*v1.w;
    s = wave_sum64(s);
    float nrm = sqrtf(s);
    if (lane == 0) xnorm[row] = nrm;
    float inv = 1.0f / nrm;
    uint2 q = pack8_fp8(v0.x*inv, v0.y*inv, v0.z*inv, v0.w*inv,
                        v1.x*inv, v1.y*inv, v1.z*inv, v1.w*inv);
    *(uint2*)(xn8 + row * D_DIM + lane * 8) = q;
}

// K2: per-row target logit + margin terms; target w-norm computed inline.
// grid 512 x 64
__global__ void k_tlogit(const float* __restrict__ x, const float* __restrict__ w,
                         const float* __restrict__ xnorm,
                         const int* __restrict__ target,
                         float* __restrict__ tl, float* __restrict__ ctm,
                         float* __restrict__ ftl) {
    int row = blockIdx.x;
    int lane = threadIdx.x;
    int tgt = target[row];
    const float* xr = x + row * D_DIM + lane * 8;
    const float* wr = w + (size_t)tgt * D_DIM + lane * 8;
    float4 a0 = *(const float4*)(xr),     a1 = *(const float4*)(xr + 4);
    float4 b0 = *(const float4*)(wr),     b1 = *(const float4*)(wr + 4);
    float s = a0.x*b0.x + a0.y*b0.y + a0.z*b0.z + a0.w*b0.w
            + a1.x*b1.x + a1.y*b1.y + a1.z*b1.z + a1.w*b1.w;
    float q = b0.x*b0.x + b0.y*b0.y + b0.z*b0.z + b0.w*b0.w
            + b1.x*b1.x + b1.y*b1.y + b1.z*b1.z + b1.w*b1.w;
    s = wave_sum64(s);
    q = wave_sum64(q);
    if (lane == 0) {
        float c = s / (xnorm[row] * sqrtf(q));
        c = fminf(fmaxf(c, -1.0f + EPS_F), 1.0f - EPS_F);
        float sn = sqrtf(fmaxf(1.0f - c * c, 0.0f));
        float cm = c * COS_M_F - sn * SIN_M_F;
        tl[row]  = c;
        ctm[row] = cm;
        ftl[row] = (c > THRESH_F) ? cm : (c - MM_F);
    }
}

// K2b: t_new = mean(tl)*0.01 + 0.99*t.  1 x 512
__global__ void k_tnew(const float* __restrict__ tl, const float* __restrict__ t,
                       float* __restrict__ tnew) {
    __shared__ float s[512];
    int tid = threadIdx.x;
    s[tid] = tl[tid];
    __syncthreads();
    for (int off = 256; off > 0; off >>= 1) {
        if (tid < off) s[tid] += s[tid + off];
        __syncthreads();
    }
    if (tid == 0) tnew[0] = (s[0] / 512.0f) * 0.01f + 0.99f * t[0];
}

// ---------------------------------------------------------------------------
// K3: FUSED single-pass kernel with COUNTED-vmcnt pipeline (T4).
//  Each block: ALL 512 rows x 64 classes; w read exactly once chip-wide.
//  Per step, vmem issue order pinned via sched_barrier(0):
//    [2x global_load_lds (A, next slice)] ... [1x global_load (B, slice+3)]
//  then s_waitcnt vmcnt(1) (A drained, newest B load stays IN FLIGHT across
//  the raw s_barrier) — the B HBM load gets ~2 steps of cover instead of 0.
//  Tail steps (kk=13,14) use vmcnt(0) (no new B load -> exact count).
// grid 1564 x 512
// ---------------------------------------------------------------------------
__global__ __launch_bounds__(512, 4) void k_fused(
        const unsigned char* __restrict__ xn8,    // fp8 [512][512], normalized
        const float* __restrict__ w,              // f32 [100000][512] RAW
        const int* __restrict__ target,
        const float* __restrict__ ctm,
        const float* __restrict__ ftl,
        const float* __restrict__ tnew,
        float* __restrict__ psum) {               // [NG2][512]
    __shared__ unsigned char As[2][512 * 32];     // 2 x 16 KB
    __shared__ unsigned char Bs[2][64 * 32];      // 2 x 2 KB
    __shared__ float invS[64];
    __shared__ int   tgt_s[512];
    __shared__ float ctm_s[512];
    __shared__ float ftl_s[512];

    int bx = blockIdx.x;
    int cb = bx * NC;                  // first class of this block
    int tid = threadIdx.x;
    int lane = tid & 63, wid = tid >> 6;
    int fr = lane & 15, rgrp = lane >> 4;
    int wrow = wid * 64;               // wave's first A-row

    tgt_s[tid] = target[tid];
    ctm_s[tid] = ctm[tid];
    ftl_s[tid] = ftl[tid];
    float tn = tnew[0];                // issued before the counted region

    // ---- B staging assignment: thread -> (class-row, 4-f32 slot) ----
    int brow  = tid >> 3;              // 0..63
    int bslot = tid & 7;               // 0..7
    int bclass = cb + brow;
    bool brvalid = (bclass < C_CLS);
    const float* bsrc = w + (size_t)(brvalid ? bclass : 0) * D_DIM + bslot * 4;

    float sumsq = 0.0f;

    // stage A slice kk into As[buf] (2 x 8 KB global_load_lds, linear)
    #define STAGE_A(kk, buf)                                                  \
        do {                                                                  \
            _Pragma("unroll")                                                 \
            for (int c = 0; c < 2; ++c) {                                     \
                int lo = c * 8192 + wid * 1024;      /* wave-uniform */       \
                int o  = lo + lane * 16;                                      \
                int row = o >> 5, b = o & 31;                                 \
                GLOAD_LDS16(xn8 + (size_t)row * 512 + (kk) * 32 + b,          \
                            (char*)As[buf] + lo);                             \
            }                                                                 \
        } while (0)

    // write a previously-loaded B slice into Bs[buf]: sumsq + cvt + ds_write
    #define WRITE_B(vv, buf)                                                  \
        do {                                                                  \
            sumsq += vv.x*vv.x + vv.y*vv.y + vv.z*vv.z + vv.w*vv.w;           \
            *(unsigned*)(&Bs[buf][brow * 32 + bslot * 4]) =                   \
                pack4_fp8(vv.x, vv.y, vv.z, vv.w);                            \
        } while (0)

    // ---- prologue: pin vmem order [v0, A, A] sb [rv1, rv2] ----
    __builtin_amdgcn_sched_barrier(0);
    float4 v0 = *(const float4*)(bsrc);                 // slice 0
    STAGE_A(0, 0);
    __builtin_amdgcn_sched_barrier(0);
    float4 rv_next = *(const float4*)(bsrc + 1 * 32);   // slice 1
    float4 rv_far  = *(const float4*)(bsrc + 2 * 32);   // slice 2
    WRITE_B(v0, 0);                                     // waits v0 (reg dep)
    asm volatile("s_waitcnt vmcnt(2) lgkmcnt(0)" ::: "memory");  // A drained; rv1,rv2 fly
    __builtin_amdgcn_sched_barrier(0);
    __builtin_amdgcn_s_barrier();
    __builtin_amdgcn_sched_barrier(0);

    f32x4 acc[4][4];                   // [m][j]
    #pragma unroll
    for (int m = 0; m < 4; m++)
        #pragma unroll
        for (int j = 0; j < 4; j++)
            acc[m][j] = (f32x4){0.f, 0.f, 0.f, 0.f};

    union LL { uint2 u; long long ll; };

    #pragma unroll
    for (int kk = 0; kk < 16; ++kk) {
        int cur = kk & 1;
        if (kk < 15) {
            STAGE_A(kk + 1, cur ^ 1);          // vmem FIRST (2 ops)
            __builtin_amdgcn_sched_barrier(0);
            WRITE_B(rv_next, cur ^ 1);         // ds_write (reg-dep wait only)
            rv_next = rv_far;
            if (kk < 13)
                rv_far = *(const float4*)(bsrc + (kk + 3) * 32);  // vmem LAST
        }
        // frags from current buffers
        uint2 af[4], bf[4];
        #pragma unroll
        for (int m = 0; m < 4; m++)
            af[m] = *(const uint2*)(&As[cur][(wrow + m * 16 + fr) * 32 + rgrp * 8]);
        #pragma unroll
        for (int j = 0; j < 4; j++)
            bf[j] = *(const uint2*)(&Bs[cur][(j * 16 + fr) * 32 + rgrp * 8]);
        __builtin_amdgcn_s_setprio(1);
        #pragma unroll
        for (int m = 0; m < 4; m++)
            #pragma unroll
            for (int j = 0; j < 4; j++) {
                LL a, b;
                a.u = af[m];
                b.u = bf[j];
                acc[m][j] = __builtin_amdgcn_mfma_f32_16x16x32_fp8_fp8(
                                a.ll, b.ll, acc[m][j], 0, 0, 0);
            }
        __builtin_amdgcn_s_setprio(0);
        if (kk < 15) {
            // counted drain: A-stage (and older) retired; newest B load stays
            // in flight across the barrier (in-order vmcnt retirement).
            if (kk < 13)
                asm volatile("s_waitcnt vmcnt(1) lgkmcnt(0)" ::: "memory");
            else
                asm volatile("s_waitcnt vmcnt(0) lgkmcnt(0)" ::: "memory");
            __builtin_amdgcn_sched_barrier(0);
            __builtin_amdgcn_s_barrier();
            __builtin_amdgcn_sched_barrier(0);
        }
    }
    #undef STAGE_A
    #undef WRITE_B

    // ---- combine sumsq (8 threads per class row) -> invS ----
    float s2 = sumsq;
    s2 += __shfl_xor(s2, 1);
    s2 += __shfl_xor(s2, 2);
    s2 += __shfl_xor(s2, 4);
    if (bslot == 0) invS[brow] = rsqrtf(s2);
    __syncthreads();                   // full drain (one-time) before invS reads

    // ---- epilogue: fixed-max transform + exp + row sum ----
    // C/D layout: col = cb + j*16 + fr, row = wrow + m*16 + rgrp*4 + reg.
    float inv[4];
    bool cvalid[4];
    #pragma unroll
    for (int j = 0; j < 4; j++) {
        inv[j] = invS[j * 16 + fr];
        cvalid[j] = (cb + j * 16 + fr) < C_CLS;
    }
    #pragma unroll
    for (int m = 0; m < 4; m++) {
        #pragma unroll
        for (int reg = 0; reg < 4; reg++) {
            int rl = wrow + m * 16 + rgrp * 4 + reg;
            int tr = tgt_s[rl];
            float cm = ctm_s[rl];
            float ft = ftl_s[rl];
            float sm = 0.0f;
            #pragma unroll
            for (int j = 0; j < 4; j++) {
                int col = cb + j * 16 + fr;
                float c = acc[m][j][reg] * inv[j];
                c = fminf(fmaxf(c, -1.0f + EPS_F), 1.0f - EPS_F);
                float v = (c > cm) ? c * (tn + c) : c;
                v *= SCALE_F;
                v = (col == tr) ? ft * SCALE_F : v;
                v = cvalid[j] ? v : -3.0e38f;   // exp -> 0
                sm += __expf(v - FIXMAX_F);
            }
            #pragma unroll
            for (int msk = 1; msk < 16; msk <<= 1) sm += __shfl_xor(sm, msk);
            if (fr == 0) psum[(size_t)bx * 512 + rl] = sm;   // coalesced
        }
    }
}

// K4: per-row sum over NG2 partials (fixed max) -> loss_i.  grid 512 x 256
// psum is [nb][row]; reads are strided but L2-resident (3.2 MB).
__global__ void k_rowlse_fix(const float* __restrict__ psum,
                             const float* __restrict__ ftl,
                             float* __restrict__ lossi) {
    int row = blockIdx.x, tid = threadIdx.x;
    float S = 0.0f;
    for (int nb = tid; nb < NG2; nb += 256) S += psum[(size_t)nb * 512 + row];
    __shared__ float sS[256];
    sS[tid] = S;
    __syncthreads();
    for (int off = 128; off > 0; off >>= 1) {
        if (tid < off) sS[tid] += sS[tid + off];
        __syncthreads();
    }
    if (tid == 0) lossi[row] = logf(sS[0]) + FIXMAX_F - SCALE_F * ftl[row];
}

// K5: loss = mean(loss_i).  1 x 512
__global__ void k_final(const float* __restrict__ lossi, float* __restrict__ out) {
    __shared__ float s[512];
    int tid = threadIdx.x;
    s[tid] = lossi[tid];
    __syncthreads();
    for (int off = 256; off > 0; off >>= 1) {
        if (tid < off) s[tid] += s[tid + off];
        __syncthreads();
    }
    if (tid == 0) out[0] = s[0] / 512.0f;
}

extern "C" void kernel_launch(void* const* d_in, const int* in_sizes, int n_in,
                              void* d_out, int out_size, void* d_ws, size_t ws_size,
                              hipStream_t stream) {
    const float* x      = (const float*)d_in[0];
    const float* w      = (const float*)d_in[1];
    const float* t      = (const float*)d_in[2];
    const int*   target = (const int*)d_in[3];

    char* ws = (char*)d_ws;
    unsigned char* xn8  = (unsigned char*)(ws + XN8_OFF);
    float* tl    = (float*)(ws + TL_OFF);
    float* ctm   = (float*)(ws + CTM_OFF);
    float* ftl   = (float*)(ws + FTL_OFF);
    float* tnew  = (float*)(ws + TNEW_OFF);
    float* xnorm = (float*)(ws + XNORM_OFF);
    float* psum  = (float*)(ws + PSUM_OFF);
    float* lossi = (float*)(ws + LOSSI_OFF);
    float* out   = (float*)d_out;

    k_xnorm_fp8<<<dim3(N_ROWS), dim3(64), 0, stream>>>(x, xn8, xnorm);
    k_tlogit<<<dim3(N_ROWS), dim3(64), 0, stream>>>(x, w, xnorm, target, tl, ctm, ftl);
    k_tnew<<<dim3(1), dim3(512), 0, stream>>>(tl, t, tnew);
    k_fused<<<dim3(NG2), dim3(512), 0, stream>>>(xn8, w, target, ctm, ftl, tnew, psum);
    k_rowlse_fix<<<dim3(N_ROWS), dim3(256), 0, stream>>>(psum, ftl, lossi);
    k_final<<<dim3(1), dim3(512), 0, stream>>>(lossi, out);
}

// Round 15
// 122.789 us; speedup vs baseline: 1.0078x; 1.0001x over previous
//
#include <hip/hip_runtime.h>
#include <hip/hip_bf16.h>
#include <stdint.h>

#define N_ROWS 512
#define D_DIM  512
#define C_CLS  100000

#define SCALE_F    64.0f
#define EPS_F      1e-7f
#define COS_M_F    0.8775825618903728f
#define SIN_M_F    0.4794255386042030f
#define THRESH_F  -0.8775825618903728f
#define MM_F       0.2397127693021015f
#define FIXMAX_F   65.0f        // fixed softmax max: all logits <= ~64.7 < 65

#define NC  64          // classes per block
#define NG2 1564        // ceil(100000/64) -> 1564*64 = 100096

// ---- ws layout (bytes) ----
#define XN8_OFF    0                          // fp8 [512][512] = 256 KB
#define TL_OFF     (XN8_OFF + 512*512)        // f32 [512]
#define CTM_OFF    (TL_OFF + 2048)            // f32 [512]
#define FTL_OFF    (CTM_OFF + 2048)           // f32 [512]
#define TNEW_OFF   (FTL_OFF + 2048)           // f32 [1] (padded)
#define XNORM_OFF  (TNEW_OFF + 256)           // f32 [512]
#define PSUM_OFF   (XNORM_OFF + 2048)         // f32 [NG2][512] = 3.2 MB (transposed)
#define LOSSI_OFF  (PSUM_OFF + NG2*512*4)     // f32 [512]

typedef __attribute__((ext_vector_type(4))) float f32x4;

#define GLOAD_LDS16(gp, lp) \
    __builtin_amdgcn_global_load_lds((const __attribute__((address_space(1))) void*)(gp), \
                                     (__attribute__((address_space(3))) void*)(lp), 16, 0, 0)

#if defined(__has_builtin)
#if __has_builtin(__builtin_amdgcn_cvt_pk_fp8_f32)
#define HAVE_CVT_FP8 1
#endif
#endif

// manual OCP e4m3fn fallback (round-to-nearest; saturating; no inf)
__device__ inline unsigned char f2e4m3(float f) {
    union { float f; unsigned u; } a; a.f = f;
    unsigned s = (a.u >> 24) & 0x80u;
    float af = fabsf(f);
    if (af < 0.015625f) {
        int q = (int)(af * 512.0f + 0.5f);
        return (unsigned char)(s | (unsigned)q);
    }
    unsigned x = a.u & 0x7FFFFFFFu;
    unsigned r = x + 0x000FFFFFu + ((x >> 20) & 1u);
    int ec = (int)(r >> 23) - 127 + 7;
    unsigned m = (r >> 20) & 7u;
    if (ec > 15 || (ec == 15 && m == 7u)) return (unsigned char)(s | 0x7Eu);
    return (unsigned char)(s | ((unsigned)ec << 3) | m);
}

__device__ inline unsigned pack4_fp8(float f0, float f1, float f2, float f3) {
#ifdef HAVE_CVT_FP8
    int q = __builtin_amdgcn_cvt_pk_fp8_f32(f0, f1, 0, false);
    q     = __builtin_amdgcn_cvt_pk_fp8_f32(f2, f3, q, true);
    return (unsigned)q;
#else
    union { unsigned char b[4]; unsigned u; } u;
    u.b[0]=f2e4m3(f0); u.b[1]=f2e4m3(f1); u.b[2]=f2e4m3(f2); u.b[3]=f2e4m3(f3);
    return u.u;
#endif
}

__device__ inline uint2 pack8_fp8(float f0, float f1, float f2, float f3,
                                  float f4, float f5, float f6, float f7) {
    uint2 r;
    r.x = pack4_fp8(f0, f1, f2, f3);
    r.y = pack4_fp8(f4, f5, f6, f7);
    return r;
}

__device__ inline float wave_sum64(float v) {
    #pragma unroll
    for (int m = 1; m < 64; m <<= 1) v += __shfl_xor(v, m);
    return v;
}

// K1: x row norms + xn fp8.  grid 512 x 64
__global__ void k_xnorm_fp8(const float* __restrict__ x,
                            unsigned char* __restrict__ xn8,
                            float* __restrict__ xnorm) {
    int row = blockIdx.x;
    int lane = threadIdx.x;
    const float* xr = x + row * D_DIM + lane * 8;
    float4 v0 = *(const float4*)(xr);
    float4 v1 = *(const float4*)(xr + 4);
    float s = v0.x*v0.x + v0.y*v0.y + v0.z*v0.z + v0.w*v0.w
            + v1.x*v1.x + v1.y*v1.y + v1.z*v1.z + v1.w*v1.w;
    s = wave_sum64(s);
    float nrm = sqrtf(s);
    if (lane == 0) xnorm[row] = nrm;
    float inv = 1.0f / nrm;
    uint2 q = pack8_fp8(v0.x*inv, v0.y*inv, v0.z*inv, v0.w*inv,
                        v1.x*inv, v1.y*inv, v1.z*inv, v1.w*inv);
    *(uint2*)(xn8 + row * D_DIM + lane * 8) = q;
}

// K2: per-row target logit + margin terms; target w-norm computed inline.
// grid 512 x 64
__global__ void k_tlogit(const float* __restrict__ x, const float* __restrict__ w,
                         const float* __restrict__ xnorm,
                         const int* __restrict__ target,
                         float* __restrict__ tl, float* __restrict__ ctm,
                         float* __restrict__ ftl) {
    int row = blockIdx.x;
    int lane = threadIdx.x;
    int tgt = target[row];
    const float* xr = x + row * D_DIM + lane * 8;
    const float* wr = w + (size_t)tgt * D_DIM + lane * 8;
    float4 a0 = *(const float4*)(xr),     a1 = *(const float4*)(xr + 4);
    float4 b0 = *(const float4*)(wr),     b1 = *(const float4*)(wr + 4);
    float s = a0.x*b0.x + a0.y*b0.y + a0.z*b0.z + a0.w*b0.w
            + a1.x*b1.x + a1.y*b1.y + a1.z*b1.z + a1.w*b1.w;
    float q = b0.x*b0.x + b0.y*b0.y + b0.z*b0.z + b0.w*b0.w
            + b1.x*b1.x + b1.y*b1.y + b1.z*b1.z + b1.w*b1.w;
    s = wave_sum64(s);
    q = wave_sum64(q);
    if (lane == 0) {
        float c = s / (xnorm[row] * sqrtf(q));
        c = fminf(fmaxf(c, -1.0f + EPS_F), 1.0f - EPS_F);
        float sn = sqrtf(fmaxf(1.0f - c * c, 0.0f));
        float cm = c * COS_M_F - sn * SIN_M_F;
        tl[row]  = c;
        ctm[row] = cm;
        ftl[row] = (c > THRESH_F) ? cm : (c - MM_F);
    }
}

// K2b: t_new = mean(tl)*0.01 + 0.99*t.  1 x 512
__global__ void k_tnew(const float* __restrict__ tl, const float* __restrict__ t,
                       float* __restrict__ tnew) {
    __shared__ float s[512];
    int tid = threadIdx.x;
    s[tid] = tl[tid];
    __syncthreads();
    for (int off = 256; off > 0; off >>= 1) {
        if (tid < off) s[tid] += s[tid + off];
        __syncthreads();
    }
    if (tid == 0) tnew[0] = (s[0] / 512.0f) * 0.01f + 0.99f * t[0];
}

// ---------------------------------------------------------------------------
// K3: FUSED single-pass kernel, BK=64 (8 barrier steps instead of 16).
//  Each block: ALL 512 rows x 64 classes; w read exactly once chip-wide.
//  Per step: A slice = 512 rows x 64 B (global_load_lds x4/thread, source
//  pre-swizzled 16B-granule XOR); B slice = 64 rows x 64 f32 (2 float4/thread,
//  register ring 2 deep, cvt fp8 once, 8-B swizzled ds_write); 32 MFMA/wave.
//  Counted vmcnt: end-of-step vmcnt(2) keeps this step's 2 B loads in flight
//  across the raw s_barrier (tail: vmcnt(0)).  XOR swizzle both-sides
//  (rule #21): LDS[row][b] holds src byte b ^ ((row&3)<<4).
// grid 1564 x 512
// ---------------------------------------------------------------------------
__global__ __launch_bounds__(512, 4) void k_fused(
        const unsigned char* __restrict__ xn8,    // fp8 [512][512], normalized
        const float* __restrict__ w,              // f32 [100000][512] RAW
        const int* __restrict__ target,
        const float* __restrict__ ctm,
        const float* __restrict__ ftl,
        const float* __restrict__ tnew,
        float* __restrict__ psum) {               // [NG2][512]
    __shared__ unsigned char As[2][512 * 64];     // 2 x 32 KB
    __shared__ unsigned char Bs[2][64 * 64];      // 2 x 4 KB
    __shared__ float invS[64];
    __shared__ int   tgt_s[512];
    __shared__ float ctm_s[512];
    __shared__ float ftl_s[512];

    int bx = blockIdx.x;
    int cb = bx * NC;                  // first class of this block
    int tid = threadIdx.x;
    int lane = tid & 63, wid = tid >> 6;
    int fr = lane & 15, rgrp = lane >> 4;
    int wrow = wid * 64;               // wave's first A-row

    tgt_s[tid] = target[tid];
    ctm_s[tid] = ctm[tid];
    ftl_s[tid] = ftl[tid];
    float tn = tnew[0];                // issued before the counted region

    // ---- B staging assignment: thread -> (class-row, 8-f32 slot) ----
    int brow  = tid >> 3;              // 0..63
    int bslot = tid & 7;               // 0..7
    int bclass = cb + brow;
    bool brvalid = (bclass < C_CLS);
    const float* bsrc = w + (size_t)(brvalid ? bclass : 0) * D_DIM + bslot * 8;

    float sumsq = 0.0f;
    int bwaddr = brow * 64 + ((bslot * 8) ^ ((brow & 3) << 4));  // swizzled

    // stage A slice kk (512 rows x 64 B) into As[buf]; source pre-swizzled.
    #define STAGE_A(kk, buf)                                                  \
        do {                                                                  \
            _Pragma("unroll")                                                 \
            for (int c = 0; c < 4; ++c) {                                     \
                int lo = c * 8192 + wid * 1024;      /* wave-uniform */       \
                int o  = lo + lane * 16;                                      \
                int row = o >> 6, b = o & 63;                                 \
                GLOAD_LDS16(xn8 + (size_t)row * 512 + (kk) * 64               \
                                + (b ^ ((row & 3) << 4)),                     \
                            (char*)As[buf] + lo);                             \
            }                                                                 \
        } while (0)

    // write a previously-loaded B slice (2 float4) into Bs[buf]
    #define WRITE_B(va, vb, buf)                                              \
        do {                                                                  \
            sumsq += va.x*va.x + va.y*va.y + va.z*va.z + va.w*va.w            \
                   + vb.x*vb.x + vb.y*vb.y + vb.z*vb.z + vb.w*vb.w;           \
            uint2 pk_;                                                        \
            pk_.x = pack4_fp8(va.x, va.y, va.z, va.w);                        \
            pk_.y = pack4_fp8(vb.x, vb.y, vb.z, vb.w);                        \
            *(uint2*)(&Bs[buf][bwaddr]) = pk_;                                \
        } while (0)

    // ---- prologue: order [v0 x2, A(0) x4] sb [ring x4] ----
    __builtin_amdgcn_sched_barrier(0);
    float4 v0a = *(const float4*)(bsrc);                // slice 0
    float4 v0b = *(const float4*)(bsrc + 4);
    STAGE_A(0, 0);
    __builtin_amdgcn_sched_barrier(0);
    float4 rv_next0 = *(const float4*)(bsrc + 1 * 64);  // slice 1
    float4 rv_next1 = *(const float4*)(bsrc + 1 * 64 + 4);
    float4 rv_far0  = *(const float4*)(bsrc + 2 * 64);  // slice 2
    float4 rv_far1  = *(const float4*)(bsrc + 2 * 64 + 4);
    WRITE_B(v0a, v0b, 0);                               // waits v0 (reg dep)
    asm volatile("s_waitcnt vmcnt(4) lgkmcnt(0)" ::: "memory"); // A drained; ring flies
    __builtin_amdgcn_sched_barrier(0);
    __builtin_amdgcn_s_barrier();
    __builtin_amdgcn_sched_barrier(0);

    f32x4 acc[4][4];                   // [m][j]
    #pragma unroll
    for (int m = 0; m < 4; m++)
        #pragma unroll
        for (int j = 0; j < 4; j++)
            acc[m][j] = (f32x4){0.f, 0.f, 0.f, 0.f};

    union LL { uint2 u; long long ll; };
    int akey = (fr & 3) << 4;          // read-side XOR (row&3 == fr&3)

    #pragma unroll
    for (int kk = 0; kk < 8; ++kk) {
        int cur = kk & 1;
        if (kk < 7) {
            STAGE_A(kk + 1, cur ^ 1);          // vmem FIRST (4 ops)
            __builtin_amdgcn_sched_barrier(0);
            WRITE_B(rv_next0, rv_next1, cur ^ 1);
            rv_next0 = rv_far0;
            rv_next1 = rv_far1;
            if (kk < 5) {                       // vmem LAST (2 ops)
                rv_far0 = *(const float4*)(bsrc + (kk + 3) * 64);
                rv_far1 = *(const float4*)(bsrc + (kk + 3) * 64 + 4);
            }
        }
        // compute: 2 sub-slices x 16 MFMA
        #pragma unroll
        for (int sub = 0; sub < 2; ++sub) {
            uint2 af[4], bf[4];
            int soff = (sub * 32 + rgrp * 8) ^ akey;
            #pragma unroll
            for (int m = 0; m < 4; m++)
                af[m] = *(const uint2*)(&As[cur][(wrow + m * 16 + fr) * 64 + soff]);
            #pragma unroll
            for (int j = 0; j < 4; j++)
                bf[j] = *(const uint2*)(&Bs[cur][(j * 16 + fr) * 64 + soff]);
            __builtin_amdgcn_s_setprio(1);
            #pragma unroll
            for (int m = 0; m < 4; m++)
                #pragma unroll
                for (int j = 0; j < 4; j++) {
                    LL a, b;
                    a.u = af[m];
                    b.u = bf[j];
                    acc[m][j] = __builtin_amdgcn_mfma_f32_16x16x32_fp8_fp8(
                                    a.ll, b.ll, acc[m][j], 0, 0, 0);
                }
            __builtin_amdgcn_s_setprio(0);
        }
        if (kk < 7) {
            // counted drain: A-stage retired; this step's B loads stay in
            // flight across the barrier (in-order vmcnt retirement).
            if (kk < 5)
                asm volatile("s_waitcnt vmcnt(2) lgkmcnt(0)" ::: "memory");
            else
                asm volatile("s_waitcnt vmcnt(0) lgkmcnt(0)" ::: "memory");
            __builtin_amdgcn_sched_barrier(0);
            __builtin_amdgcn_s_barrier();
            __builtin_amdgcn_sched_barrier(0);
        }
    }
    #undef STAGE_A
    #undef WRITE_B

    // ---- combine sumsq (8 threads per class row) -> invS ----
    float s2 = sumsq;
    s2 += __shfl_xor(s2, 1);
    s2 += __shfl_xor(s2, 2);
    s2 += __shfl_xor(s2, 4);
    if (bslot == 0) invS[brow] = rsqrtf(s2);
    __syncthreads();                   // full drain (one-time) before invS reads

    // ---- epilogue: fixed-max transform + exp + row sum ----
    // C/D layout: col = cb + j*16 + fr, row = wrow + m*16 + rgrp*4 + reg.
    float inv[4];
    bool cvalid[4];
    #pragma unroll
    for (int j = 0; j < 4; j++) {
        inv[j] = invS[j * 16 + fr];
        cvalid[j] = (cb + j * 16 + fr) < C_CLS;
    }
    #pragma unroll
    for (int m = 0; m < 4; m++) {
        #pragma unroll
        for (int reg = 0; reg < 4; reg++) {
            int rl = wrow + m * 16 + rgrp * 4 + reg;
            int tr = tgt_s[rl];
            float cm = ctm_s[rl];
            float ft = ftl_s[rl];
            float sm = 0.0f;
            #pragma unroll
            for (int j = 0; j < 4; j++) {
                int col = cb + j * 16 + fr;
                float c = acc[m][j][reg] * inv[j];
                c = fminf(fmaxf(c, -1.0f + EPS_F), 1.0f - EPS_F);
                float v = (c > cm) ? c * (tn + c) : c;
                v *= SCALE_F;
                v = (col == tr) ? ft * SCALE_F : v;
                v = cvalid[j] ? v : -3.0e38f;   // exp -> 0
                sm += __expf(v - FIXMAX_F);
            }
            #pragma unroll
            for (int msk = 1; msk < 16; msk <<= 1) sm += __shfl_xor(sm, msk);
            if (fr == 0) psum[(size_t)bx * 512 + rl] = sm;   // coalesced
        }
    }
}

// K4: per-row sum over NG2 partials (fixed max) -> loss_i.  grid 512 x 256
// psum is [nb][row]; reads are strided but L2-resident (3.2 MB).
__global__ void k_rowlse_fix(const float* __restrict__ psum,
                             const float* __restrict__ ftl,
                             float* __restrict__ lossi) {
    int row = blockIdx.x, tid = threadIdx.x;
    float S = 0.0f;
    for (int nb = tid; nb < NG2; nb += 256) S += psum[(size_t)nb * 512 + row];
    __shared__ float sS[256];
    sS[tid] = S;
    __syncthreads();
    for (int off = 128; off > 0; off >>= 1) {
        if (tid < off) sS[tid] += sS[tid + off];
        __syncthreads();
    }
    if (tid == 0) lossi[row] = logf(sS[0]) + FIXMAX_F - SCALE_F * ftl[row];
}

// K5: loss = mean(loss_i).  1 x 512
__global__ void k_final(const float* __restrict__ lossi, float* __restrict__ out) {
    __shared__ float s[512];
    int tid = threadIdx.x;
    s[tid] = lossi[tid];
    __syncthreads();
    for (int off = 256; off > 0; off >>= 1) {
        if (tid < off) s[tid] += s[tid + off];
        __syncthreads();
    }
    if (tid == 0) out[0] = s[0] / 512.0f;
}

extern "C" void kernel_launch(void* const* d_in, const int* in_sizes, int n_in,
                              void* d_out, int out_size, void* d_ws, size_t ws_size,
                              hipStream_t stream) {
    const float* x      = (const float*)d_in[0];
    const float* w      = (const float*)d_in[1];
    const float* t      = (const float*)d_in[2];
    const int*   target = (const int*)d_in[3];

    char* ws = (char*)d_ws;
    unsigned char* xn8  = (unsigned char*)(ws + XN8_OFF);
    float* tl    = (float*)(ws + TL_OFF);
    float* ctm   = (float*)(ws + CTM_OFF);
    float* ftl   = (float*)(ws + FTL_OFF);
    float* tnew  = (float*)(ws + TNEW_OFF);
    float* xnorm = (float*)(ws + XNORM_OFF);
    float* psum  = (float*)(ws + PSUM_OFF);
    float* lossi = (float*)(ws + LOSSI_OFF);
    float* out   = (float*)d_out;

    k_xnorm_fp8<<<dim3(N_ROWS), dim3(64), 0, stream>>>(x, xn8, xnorm);
    k_tlogit<<<dim3(N_ROWS), dim3(64), 0, stream>>>(x, w, xnorm, target, tl, ctm, ftl);
    k_tnew<<<dim3(1), dim3(512), 0, stream>>>(tl, t, tnew);
    k_fused<<<dim3(NG2), dim3(512), 0, stream>>>(xn8, w, target, ctm, ftl, tnew, psum);
    k_rowlse_fix<<<dim3(N_ROWS), dim3(256), 0, stream>>>(psum, ftl, lossi);
    k_final<<<dim3(1), dim3(512), 0, stream>>>(lossi, out);
}